// Round 12
// baseline (2837.820 us; speedup 1.0000x reference)
//
#include <hip/hip_runtime.h>
#include <cstdint>
#include <cstddef>

#define S_LEN 2048
#define BATCH 64
#define ISZ   256
#define HSZ   128

typedef __attribute__((ext_vector_type(8))) short short8;   // 8 bf16 = 4 VGPR
typedef __attribute__((ext_vector_type(4))) float f32x4;    // MFMA acc

__device__ __forceinline__ uint32_t bfh(float x)   // fp32 -> bf16 bits (RNE)
{
    uint32_t u = __float_as_uint(x);
    u += 0x7fffu + ((u >> 16) & 1u);
    return u >> 16;
}
__device__ __forceinline__ unsigned short f2bf(float x) { return (unsigned short)bfh(x); }

// ---------------------------------------------------------------------------
// Split-precision bf16 MFMA GEMM (r10, validated): C = A @ W^T (+bias)
// ---------------------------------------------------------------------------
__device__ __forceinline__ void stage_tile(const float* __restrict__ src, int row0,
                                           int K, int k0, int tid,
                                           short* __restrict__ hi, short* __restrict__ lo)
{
    #pragma unroll
    for (int it = 0; it < 4; ++it) {
        const int g   = tid + it * 256;
        const int row = g >> 3;
        const int kg  = (g & 7) * 8;
        const float* p = src + (size_t)(row0 + row) * K + k0 + kg;
        const float4 v0 = *reinterpret_cast<const float4*>(p);
        const float4 v1 = *reinterpret_cast<const float4*>(p + 4);
        const float f[8] = {v0.x, v0.y, v0.z, v0.w, v1.x, v1.y, v1.z, v1.w};
        uint32_t hp[4], lp[4];
        #pragma unroll
        for (int i = 0; i < 4; ++i) {
            const uint32_t h0 = bfh(f[2*i]), h1 = bfh(f[2*i+1]);
            const float r0 = f[2*i]   - __uint_as_float(h0 << 16);
            const float r1 = f[2*i+1] - __uint_as_float(h1 << 16);
            hp[i] = h0 | (h1 << 16);
            lp[i] = bfh(r0) | (bfh(r1) << 16);
        }
        *reinterpret_cast<uint4*>(&hi[row*72 + kg]) = make_uint4(hp[0], hp[1], hp[2], hp[3]);
        *reinterpret_cast<uint4*>(&lo[row*72 + kg]) = make_uint4(lp[0], lp[1], lp[2], lp[3]);
    }
}

template<int LAYOUT>
__global__ __launch_bounds__(256, 2)
void gemm_mfma(const float* __restrict__ A, const float* __restrict__ W,
               const float* __restrict__ bias, float* __restrict__ C,
               int M, int N, int K)
{
    __shared__ short As_hi[128*72];
    __shared__ short As_lo[128*72];
    __shared__ short Ws_hi[128*72];
    __shared__ short Ws_lo[128*72];

    const int tid = threadIdx.x;
    const int wv  = tid >> 6;
    const int l   = tid & 63;
    const int fr  = l & 15;
    const int fk  = (l >> 4) * 8;
    const int m0  = blockIdx.y * 128;
    const int n0  = blockIdx.x * 128;

    f32x4 acc[2][8] = {};

    for (int k0 = 0; k0 < K; k0 += 64) {
        stage_tile(A, m0, K, k0, tid, As_hi, As_lo);
        stage_tile(W, n0, K, k0, tid, Ws_hi, Ws_lo);
        __syncthreads();

        #pragma unroll
        for (int ks = 0; ks < 64; ks += 32) {
            short8 ah[2], al[2], bh[8], bl[8];
            #pragma unroll
            for (int mt = 0; mt < 2; ++mt) {
                const int r = (wv*32 + mt*16 + fr) * 72 + ks + fk;
                ah[mt] = *reinterpret_cast<const short8*>(&As_hi[r]);
                al[mt] = *reinterpret_cast<const short8*>(&As_lo[r]);
            }
            #pragma unroll
            for (int nt = 0; nt < 8; ++nt) {
                const int r = (nt*16 + fr) * 72 + ks + fk;
                bh[nt] = *reinterpret_cast<const short8*>(&Ws_hi[r]);
                bl[nt] = *reinterpret_cast<const short8*>(&Ws_lo[r]);
            }
            #pragma unroll
            for (int mt = 0; mt < 2; ++mt) {
                #pragma unroll
                for (int nt = 0; nt < 8; ++nt) {
                    acc[mt][nt] = __builtin_amdgcn_mfma_f32_16x16x32_bf16(
                        ah[mt], bh[nt], acc[mt][nt], 0, 0, 0);
                    acc[mt][nt] = __builtin_amdgcn_mfma_f32_16x16x32_bf16(
                        ah[mt], bl[nt], acc[mt][nt], 0, 0, 0);
                    acc[mt][nt] = __builtin_amdgcn_mfma_f32_16x16x32_bf16(
                        al[mt], bh[nt], acc[mt][nt], 0, 0, 0);
                }
            }
        }
        __syncthreads();
    }

    const int orow = (l >> 4) * 4;
    #pragma unroll
    for (int nt = 0; nt < 8; ++nt) {
        const int n = n0 + nt*16 + fr;
        const float bv = bias ? bias[n] : 0.f;
        #pragma unroll
        for (int mt = 0; mt < 2; ++mt) {
            const int mbase = m0 + wv*32 + mt*16 + orow;
            const f32x4 a = acc[mt][nt];
            if (LAYOUT == 0) {
                #pragma unroll
                for (int r = 0; r < 4; ++r)
                    C[(size_t)(mbase + r) * N + n] = a[r] + bv;
            } else {
                float4 o;
                o.x = a[0] + bv; o.y = a[1] + bv; o.z = a[2] + bv; o.w = a[3] + bv;
                *reinterpret_cast<float4*>(
                    &C[(size_t)(mbase >> 6) * ((size_t)N * 64) +
                       (size_t)n * 64 + (mbase & 63)]) = o;
            }
        }
    }
}

// ---------------------------------------------------------------------------
// MFMA-batched GRU.  One WG per (dir, 4-batch block): grid 32, 512 threads
// = 8 waves.  Per step: D[384 gate rows][16 batch cols] = W_hh(bf16 frags,
// REGISTERS: 12 short8/thread — the only storage class proven resident
// r3-r11) @ h([batch][k] bf16 hi+lo in LDS).  Fragment layouts are the
// r10-GEMM-validated ones: A/B lane l -> row l&15, k=(l>>4)*8 (8 contig);
// D lane l -> col l&15 (batch), rows (l>>4)*4+reg.  fp32 master h lives in
// the owning thread's register; LDS bf16 hi/lo copies feed the MFMA only.
// B cols 4..15 are zero (padding).  Activation: thread t -> (j=t&127,
// b=t>>7), one per thread, exact fp32.
// ---------------------------------------------------------------------------
#define GRU_NB 4   // batches per WG

__global__ __launch_bounds__(512, 2)
void gru_mfma(const float* __restrict__ xg_f, const float* __restrict__ xg_b,
              const float* __restrict__ whh_f, const float* __restrict__ whh_b,
              const float* __restrict__ bhh_f, const float* __restrict__ bhh_b,
              const float* __restrict__ h0,     // (2,64,128)
              float* __restrict__ outs,         // (S,64,256)
              float* __restrict__ hid_out)      // (2,64,128)
{
    const int tid = threadIdx.x;          // 0..511
    const int wv  = tid >> 6;             // wave 0..7
    const int l   = tid & 63;
    const int dir = blockIdx.x >> 4;      // 16 blocks per dir
    const int bb  = blockIdx.x & 15;
    const int b0  = bb * GRU_NB;

    const float* xg  = dir ? xg_b  : xg_f;
    const float* whh = dir ? whh_b : whh_f;
    const float* bhh = dir ? bhh_b : bhh_f;

    __shared__ short hhi[16 * 136];    // h hi bf16, [bcol][k], pad 136
    __shared__ short hlo[16 * 136];    // h residual bf16
    __shared__ float gate[16 * 388];   // [bcol][row 0..383], pad 388

    // A-frags: wave wv owns rows [wv*48, wv*48+48): 3 tiles x 4 k-steps
    short8 afr[3][4];
    {
        const int arow = wv * 48 + (l & 15);
        const int akof = (l >> 4) * 8;
        #pragma unroll
        for (int rt = 0; rt < 3; ++rt) {
            #pragma unroll
            for (int ks = 0; ks < 4; ++ks) {
                const float* p = whh + (size_t)(arow + rt*16) * 128 + ks*32 + akof;
                const float4 v0 = *reinterpret_cast<const float4*>(p);
                const float4 v1 = *reinterpret_cast<const float4*>(p + 4);
                short8 s;
                s[0] = f2bf(v0.x); s[1] = f2bf(v0.y); s[2] = f2bf(v0.z); s[3] = f2bf(v0.w);
                s[4] = f2bf(v1.x); s[5] = f2bf(v1.y); s[6] = f2bf(v1.z); s[7] = f2bf(v1.w);
                afr[rt][ks] = s;
            }
        }
    }

    // activation mapping: one (j, b) per thread
    const int aj = tid & 127;
    const int ab = tid >> 7;              // 0..3
    const float bh_r = bhh[aj];
    const float bh_z = bhh[128 + aj];
    const float bh_n = bhh[256 + aj];

    // zero h arrays (padding + unused b-cols 4..15 stay zero forever)
    for (int i = tid; i < 16 * 136; i += 512) { hhi[i] = 0; hlo[i] = 0; }
    __syncthreads();

    // init h (fp32 master in register; bf16 hi/lo into LDS)
    float hj = h0[dir * (64*128) + (b0 + ab) * 128 + aj];
    {
        const uint32_t hb = bfh(hj);
        hhi[ab * 136 + aj] = (short)hb;
        hlo[ab * 136 + aj] = (short)f2bf(hj - __uint_as_float(hb << 16));
    }
    // x prefetch for t=0
    float xr, xz, xn;
    {
        const int s0 = dir ? (S_LEN - 1) : 0;
        const float* xrow = xg + ((size_t)s0 * 64 + b0 + ab) * 384;
        xr = xrow[aj]; xz = xrow[aj + 128]; xn = xrow[aj + 256];
    }
    __syncthreads();

    const int brow = (l & 15) * 136;
    const int bkof = (l >> 4) * 8;
    const int gcol = (l & 15) * 388;
    const int grow0 = wv * 48 + (l >> 4) * 4;

    for (int t = 0; t < S_LEN; ++t) {
        // issue x(t+1) prefetch first: a full step of slack
        float pxr = 0.f, pxz = 0.f, pxn = 0.f;
        if (t + 1 < S_LEN) {
            const int s1 = dir ? (S_LEN - 2 - t) : (t + 1);
            const float* xrow = xg + ((size_t)s1 * 64 + b0 + ab) * 384;
            pxr = xrow[aj]; pxz = xrow[aj + 128]; pxn = xrow[aj + 256];
        }

        // ---- phase 1: D = W_hh @ (h_hi + h_lo) ----
        f32x4 acc[3] = {};
        #pragma unroll
        for (int ks = 0; ks < 4; ++ks) {
            const short8 bh8 = *reinterpret_cast<const short8*>(&hhi[brow + ks*32 + bkof]);
            const short8 bl8 = *reinterpret_cast<const short8*>(&hlo[brow + ks*32 + bkof]);
            #pragma unroll
            for (int rt = 0; rt < 3; ++rt) {
                acc[rt] = __builtin_amdgcn_mfma_f32_16x16x32_bf16(afr[rt][ks], bh8, acc[rt], 0, 0, 0);
                acc[rt] = __builtin_amdgcn_mfma_f32_16x16x32_bf16(afr[rt][ks], bl8, acc[rt], 0, 0, 0);
            }
        }
        #pragma unroll
        for (int rt = 0; rt < 3; ++rt) {
            float4 o;
            o.x = acc[rt][0]; o.y = acc[rt][1]; o.z = acc[rt][2]; o.w = acc[rt][3];
            *reinterpret_cast<float4*>(&gate[gcol + grow0 + rt*16]) = o;
        }
        __syncthreads();

        // ---- phase 2: activation, one (j,b) per thread, exact fp32 ----
        const float hr = gate[ab*388 + aj]       + bh_r;
        const float hz = gate[ab*388 + 128 + aj] + bh_z;
        const float hn = gate[ab*388 + 256 + aj] + bh_n;
        const float r = 1.f / (1.f + __expf(-(xr + hr)));
        const float z = 1.f / (1.f + __expf(-(xz + hz)));
        const float x2 = xn + r * hn;
        const float ax = fabsf(x2);
        const float e  = __expf(-2.f * ax);
        const float nn = copysignf((1.f - e) / (1.f + e), x2);  // tanh
        const float hnew = nn + z * (hj - nn);
        hj = hnew;

        const int s = dir ? (S_LEN - 1 - t) : t;
        outs[((size_t)s * 64 + b0 + ab) * 256 + dir * 128 + aj] = hnew;

        const uint32_t hb = bfh(hnew);
        hhi[ab * 136 + aj] = (short)hb;
        hlo[ab * 136 + aj] = (short)f2bf(hnew - __uint_as_float(hb << 16));
        xr = pxr; xz = pxz; xn = pxn;
        __syncthreads();
    }

    hid_out[dir * (64*128) + (b0 + ab) * 128 + aj] = hj;
}

// ---------------------------------------------------------------------------
// Batch-axis softmax + weighted partial reduction (unchanged)
// ---------------------------------------------------------------------------
__global__ __launch_bounds__(256)
void attn_reduce(const float* __restrict__ lt,    // (S,256,64)
                 const float* __restrict__ outs,  // (S,64,256)
                 float* __restrict__ part)        // (64 chunks,64 b,256 c)
{
    __shared__ float ltile[64 * 64];
    __shared__ float otile[64 * 65];

    const int tid  = threadIdx.x;
    const int lane = tid & 63;
    const int wv   = tid >> 6;
    const int c0   = blockIdx.x * 64;
    const int sc   = blockIdx.y;

    float acc[16];
    #pragma unroll
    for (int i = 0; i < 16; ++i) acc[i] = 0.f;

    for (int si = 0; si < 32; ++si) {
        const int s = sc * 32 + si;

        const float4* src = reinterpret_cast<const float4*>(
            lt + (size_t)s * 16384 + (size_t)c0 * 64);
        #pragma unroll
        for (int i = 0; i < 4; ++i)
            reinterpret_cast<float4*>(ltile)[tid + i * 256] = src[tid + i * 256];

        #pragma unroll
        for (int i = 0; i < 4; ++i) {
            int idx = tid + i * 256;
            int bb = idx >> 4, c4 = (idx & 15) * 4;
            float4 v = *reinterpret_cast<const float4*>(
                &outs[((size_t)s * 64 + bb) * 256 + c0 + c4]);
            otile[bb*65 + c4+0] = v.x; otile[bb*65 + c4+1] = v.y;
            otile[bb*65 + c4+2] = v.z; otile[bb*65 + c4+3] = v.w;
        }
        __syncthreads();

        #pragma unroll
        for (int ci = 0; ci < 16; ++ci) {
            int c = wv * 16 + ci;
            float x = ltile[c * 64 + lane];
            float m = x;
            #pragma unroll
            for (int off = 32; off; off >>= 1)
                m = fmaxf(m, __shfl_xor(m, off));
            float e = __expf(x - m);
            float ssum = e;
            #pragma unroll
            for (int off = 32; off; off >>= 1)
                ssum += __shfl_xor(ssum, off);
            float attn = e / ssum;
            acc[ci] += attn * otile[lane * 65 + c];
        }
        __syncthreads();
    }

    #pragma unroll
    for (int ci = 0; ci < 16; ++ci) {
        int c = wv * 16 + ci;
        part[(size_t)sc * 16384 + (size_t)lane * 256 + c0 + c] = acc[ci];
    }
}

__global__ __launch_bounds__(256)
void reduce_part(const float* __restrict__ part, float* __restrict__ sent)
{
    int idx = blockIdx.x * 256 + threadIdx.x;
    float s = 0.f;
    for (int sc = 0; sc < 64; ++sc)
        s += part[(size_t)sc * 16384 + idx];
    sent[idx] = s;
}

// ---------------------------------------------------------------------------
extern "C" void kernel_launch(void* const* d_in, const int* in_sizes, int n_in,
                              void* d_out, int out_size, void* d_ws, size_t ws_size,
                              hipStream_t stream)
{
    const float* inp    = (const float*)d_in[0];
    const float* hid0   = (const float*)d_in[1];
    const float* w_ih_f = (const float*)d_in[2];
    const float* w_hh_f = (const float*)d_in[3];
    const float* b_ih_f = (const float*)d_in[4];
    const float* b_hh_f = (const float*)d_in[5];
    const float* w_ih_b = (const float*)d_in[6];
    const float* w_hh_b = (const float*)d_in[7];
    const float* b_ih_b = (const float*)d_in[8];
    const float* b_hh_b = (const float*)d_in[9];
    const float* attn_w = (const float*)d_in[10];
    const float* attn_b = (const float*)d_in[11];
    const float* comb_w = (const float*)d_in[12];

    float* out = (float*)d_out;   // [0,16384): sent, [16384,32768): hid_out

    char* ws = (char*)d_ws;
    const size_t XG_BYTES = (size_t)S_LEN * BATCH * 384 * 4;  // 201,326,592
    const size_t OS_BYTES = (size_t)S_LEN * BATCH * 256 * 4;  // 134,217,728
    if (ws_size < 2 * XG_BYTES + OS_BYTES) return;

    float* xg_f   = (float*)(ws);
    float* xg_b   = (float*)(ws + XG_BYTES);
    float* outs   = (float*)(ws + 2 * XG_BYTES);
    float* sa     = (float*)(ws);               // reuse xg_f
    float* logits = (float*)(ws + XG_BYTES);    // reuse xg_b
    float* part   = (float*)(ws);               // reuse sa

    const int M = S_LEN * BATCH;                // 131072
    dim3 blk(256);

    // K1: input-side gates, both directions (MFMA split-bf16)
    gemm_mfma<0><<<dim3(3, 1024), blk, 0, stream>>>(inp, w_ih_f, b_ih_f, xg_f, M, 384, 256);
    gemm_mfma<0><<<dim3(3, 1024), blk, 0, stream>>>(inp, w_ih_b, b_ih_b, xg_b, M, 384, 256);

    // K2: MFMA-batched bidirectional GRU (32 WGs x 512 threads)
    gru_mfma<<<dim3(32), dim3(512), 0, stream>>>(
        xg_f, xg_b, w_hh_f, w_hh_b, b_hh_f, b_hh_b, hid0, outs, out + 16384);

    // K3: sent_annotation = out_state @ attn_w^T + attn_b (MFMA)
    gemm_mfma<0><<<dim3(2, 1024), blk, 0, stream>>>(outs, attn_w, attn_b, sa, M, 256, 256);

    // K4: logits = sa @ comb_w^T, transposed (S,C,B) store (MFMA)
    gemm_mfma<1><<<dim3(2, 1024), blk, 0, stream>>>(sa, comb_w, nullptr, logits, M, 256, 256);

    // K5: softmax over batch + weighted partial sum over s-chunks
    attn_reduce<<<dim3(4, 64), blk, 0, stream>>>(logits, outs, part);

    // K6: final reduction over s-chunks -> sent
    reduce_part<<<dim3(64), blk, 0, stream>>>(part, out);
}

// Round 13
// 2796.156 us; speedup vs baseline: 1.0149x; 1.0149x over previous
//
#include <hip/hip_runtime.h>
#include <cstdint>
#include <cstddef>

#define S_LEN 2048
#define BATCH 64
#define ISZ   256
#define HSZ   128

typedef __attribute__((ext_vector_type(8))) short short8;   // 8 bf16 = 4 VGPR
typedef __attribute__((ext_vector_type(4))) float f32x4;    // MFMA acc

__device__ __forceinline__ uint32_t bfh(float x)   // fp32 -> bf16 bits (RNE)
{
    uint32_t u = __float_as_uint(x);
    u += 0x7fffu + ((u >> 16) & 1u);
    return u >> 16;
}
__device__ __forceinline__ unsigned short f2bf(float x) { return (unsigned short)bfh(x); }

// ---------------------------------------------------------------------------
// Split-precision bf16 MFMA GEMM (r10, validated): C = A @ W^T (+bias)
// ---------------------------------------------------------------------------
__device__ __forceinline__ void stage_tile(const float* __restrict__ src, int row0,
                                           int K, int k0, int tid,
                                           short* __restrict__ hi, short* __restrict__ lo)
{
    #pragma unroll
    for (int it = 0; it < 4; ++it) {
        const int g   = tid + it * 256;
        const int row = g >> 3;
        const int kg  = (g & 7) * 8;
        const float* p = src + (size_t)(row0 + row) * K + k0 + kg;
        const float4 v0 = *reinterpret_cast<const float4*>(p);
        const float4 v1 = *reinterpret_cast<const float4*>(p + 4);
        const float f[8] = {v0.x, v0.y, v0.z, v0.w, v1.x, v1.y, v1.z, v1.w};
        uint32_t hp[4], lp[4];
        #pragma unroll
        for (int i = 0; i < 4; ++i) {
            const uint32_t h0 = bfh(f[2*i]), h1 = bfh(f[2*i+1]);
            const float r0 = f[2*i]   - __uint_as_float(h0 << 16);
            const float r1 = f[2*i+1] - __uint_as_float(h1 << 16);
            hp[i] = h0 | (h1 << 16);
            lp[i] = bfh(r0) | (bfh(r1) << 16);
        }
        *reinterpret_cast<uint4*>(&hi[row*72 + kg]) = make_uint4(hp[0], hp[1], hp[2], hp[3]);
        *reinterpret_cast<uint4*>(&lo[row*72 + kg]) = make_uint4(lp[0], lp[1], lp[2], lp[3]);
    }
}

template<int LAYOUT>
__global__ __launch_bounds__(256, 2)
void gemm_mfma(const float* __restrict__ A, const float* __restrict__ W,
               const float* __restrict__ bias, float* __restrict__ C,
               int M, int N, int K)
{
    __shared__ short As_hi[128*72];
    __shared__ short As_lo[128*72];
    __shared__ short Ws_hi[128*72];
    __shared__ short Ws_lo[128*72];

    const int tid = threadIdx.x;
    const int wv  = tid >> 6;
    const int l   = tid & 63;
    const int fr  = l & 15;
    const int fk  = (l >> 4) * 8;
    const int m0  = blockIdx.y * 128;
    const int n0  = blockIdx.x * 128;

    f32x4 acc[2][8] = {};

    for (int k0 = 0; k0 < K; k0 += 64) {
        stage_tile(A, m0, K, k0, tid, As_hi, As_lo);
        stage_tile(W, n0, K, k0, tid, Ws_hi, Ws_lo);
        __syncthreads();

        #pragma unroll
        for (int ks = 0; ks < 64; ks += 32) {
            short8 ah[2], al[2], bh[8], bl[8];
            #pragma unroll
            for (int mt = 0; mt < 2; ++mt) {
                const int r = (wv*32 + mt*16 + fr) * 72 + ks + fk;
                ah[mt] = *reinterpret_cast<const short8*>(&As_hi[r]);
                al[mt] = *reinterpret_cast<const short8*>(&As_lo[r]);
            }
            #pragma unroll
            for (int nt = 0; nt < 8; ++nt) {
                const int r = (nt*16 + fr) * 72 + ks + fk;
                bh[nt] = *reinterpret_cast<const short8*>(&Ws_hi[r]);
                bl[nt] = *reinterpret_cast<const short8*>(&Ws_lo[r]);
            }
            #pragma unroll
            for (int mt = 0; mt < 2; ++mt) {
                #pragma unroll
                for (int nt = 0; nt < 8; ++nt) {
                    acc[mt][nt] = __builtin_amdgcn_mfma_f32_16x16x32_bf16(
                        ah[mt], bh[nt], acc[mt][nt], 0, 0, 0);
                    acc[mt][nt] = __builtin_amdgcn_mfma_f32_16x16x32_bf16(
                        ah[mt], bl[nt], acc[mt][nt], 0, 0, 0);
                    acc[mt][nt] = __builtin_amdgcn_mfma_f32_16x16x32_bf16(
                        al[mt], bh[nt], acc[mt][nt], 0, 0, 0);
                }
            }
        }
        __syncthreads();
    }

    const int orow = (l >> 4) * 4;
    #pragma unroll
    for (int nt = 0; nt < 8; ++nt) {
        const int n = n0 + nt*16 + fr;
        const float bv = bias ? bias[n] : 0.f;
        #pragma unroll
        for (int mt = 0; mt < 2; ++mt) {
            const int mbase = m0 + wv*32 + mt*16 + orow;
            const f32x4 a = acc[mt][nt];
            if (LAYOUT == 0) {
                #pragma unroll
                for (int r = 0; r < 4; ++r)
                    C[(size_t)(mbase + r) * N + n] = a[r] + bv;
            } else {
                float4 o;
                o.x = a[0] + bv; o.y = a[1] + bv; o.z = a[2] + bv; o.w = a[3] + bv;
                *reinterpret_cast<float4*>(
                    &C[(size_t)(mbase >> 6) * ((size_t)N * 64) +
                       (size_t)n * 64 + (mbase & 63)]) = o;
            }
        }
    }
}

// ---------------------------------------------------------------------------
// MFMA-batched GRU (r12 structure, validated: absmax 0.0156, afr resident).
// One WG per (dir, 4-batch block): grid 32, 512 threads = 8 waves.
// Per step: D[384 gate rows][16 batch cols] = W_hh(bf16 frags in registers,
// 12 short8/thread) @ h([batch][k] bf16 hi+lo in LDS).  fp32 master h in
// the owning thread's register; LDS bf16 hi/lo copies feed the MFMA only.
// r12->r13 fix: in-loop barriers are RAW s_barrier + lgkmcnt(0) only —
// __syncthreads() drains vmcnt(0) and killed the x(t+1) prefetch (~1000
// cyc/step of exposed HBM latency; r12 counters: MfmaUtil=VALUBusy=4%,
// pure latency-bound).  LDS producers are covered by lgkmcnt; global
// loads/stores deliberately stay in flight across barriers.
// ---------------------------------------------------------------------------
#define GRU_NB 4   // batches per WG

__global__ __launch_bounds__(512, 2)
void gru_mfma(const float* __restrict__ xg_f, const float* __restrict__ xg_b,
              const float* __restrict__ whh_f, const float* __restrict__ whh_b,
              const float* __restrict__ bhh_f, const float* __restrict__ bhh_b,
              const float* __restrict__ h0,     // (2,64,128)
              float* __restrict__ outs,         // (S,64,256)
              float* __restrict__ hid_out)      // (2,64,128)
{
    const int tid = threadIdx.x;          // 0..511
    const int wv  = tid >> 6;             // wave 0..7
    const int l   = tid & 63;
    const int dir = blockIdx.x >> 4;      // 16 blocks per dir
    const int bb  = blockIdx.x & 15;
    const int b0  = bb * GRU_NB;

    const float* xg  = dir ? xg_b  : xg_f;
    const float* whh = dir ? whh_b : whh_f;
    const float* bhh = dir ? bhh_b : bhh_f;

    __shared__ short hhi[16 * 136];    // h hi bf16, [bcol][k], pad 136
    __shared__ short hlo[16 * 136];    // h residual bf16
    __shared__ float gate[16 * 388];   // [bcol][row 0..383], pad 388

    // A-frags: wave wv owns rows [wv*48, wv*48+48): 3 tiles x 4 k-steps
    short8 afr[3][4];
    {
        const int arow = wv * 48 + (l & 15);
        const int akof = (l >> 4) * 8;
        #pragma unroll
        for (int rt = 0; rt < 3; ++rt) {
            #pragma unroll
            for (int ks = 0; ks < 4; ++ks) {
                const float* p = whh + (size_t)(arow + rt*16) * 128 + ks*32 + akof;
                const float4 v0 = *reinterpret_cast<const float4*>(p);
                const float4 v1 = *reinterpret_cast<const float4*>(p + 4);
                short8 s;
                s[0] = f2bf(v0.x); s[1] = f2bf(v0.y); s[2] = f2bf(v0.z); s[3] = f2bf(v0.w);
                s[4] = f2bf(v1.x); s[5] = f2bf(v1.y); s[6] = f2bf(v1.z); s[7] = f2bf(v1.w);
                afr[rt][ks] = s;
            }
        }
    }

    // activation mapping: one (j, b) per thread
    const int aj = tid & 127;
    const int ab = tid >> 7;              // 0..3
    const float bh_r = bhh[aj];
    const float bh_z = bhh[128 + aj];
    const float bh_n = bhh[256 + aj];

    // zero h arrays (padding + unused b-cols 4..15 stay zero forever)
    for (int i = tid; i < 16 * 136; i += 512) { hhi[i] = 0; hlo[i] = 0; }
    __syncthreads();

    // init h (fp32 master in register; bf16 hi/lo into LDS)
    float hj = h0[dir * (64*128) + (b0 + ab) * 128 + aj];
    {
        const uint32_t hb = bfh(hj);
        hhi[ab * 136 + aj] = (short)hb;
        hlo[ab * 136 + aj] = (short)f2bf(hj - __uint_as_float(hb << 16));
    }
    // x prefetch for t=0
    float xr, xz, xn;
    {
        const int s0 = dir ? (S_LEN - 1) : 0;
        const float* xrow = xg + ((size_t)s0 * 64 + b0 + ab) * 384;
        xr = xrow[aj]; xz = xrow[aj + 128]; xn = xrow[aj + 256];
    }
    __syncthreads();

    const int brow = (l & 15) * 136;
    const int bkof = (l >> 4) * 8;
    const int gcol = (l & 15) * 388;
    const int grow0 = wv * 48 + (l >> 4) * 4;

    for (int t = 0; t < S_LEN; ++t) {
        // issue x(t+1) prefetch first: a full step of slack, vmcnt NOT
        // drained at the raw barriers below
        float pxr = 0.f, pxz = 0.f, pxn = 0.f;
        if (t + 1 < S_LEN) {
            const int s1 = dir ? (S_LEN - 2 - t) : (t + 1);
            const float* xrow = xg + ((size_t)s1 * 64 + b0 + ab) * 384;
            pxr = xrow[aj]; pxz = xrow[aj + 128]; pxn = xrow[aj + 256];
        }

        // ---- phase 1: D = W_hh @ (h_hi + h_lo) ----
        f32x4 acc[3] = {};
        #pragma unroll
        for (int ks = 0; ks < 4; ++ks) {
            const short8 bh8 = *reinterpret_cast<const short8*>(&hhi[brow + ks*32 + bkof]);
            const short8 bl8 = *reinterpret_cast<const short8*>(&hlo[brow + ks*32 + bkof]);
            #pragma unroll
            for (int rt = 0; rt < 3; ++rt) {
                acc[rt] = __builtin_amdgcn_mfma_f32_16x16x32_bf16(afr[rt][ks], bh8, acc[rt], 0, 0, 0);
                acc[rt] = __builtin_amdgcn_mfma_f32_16x16x32_bf16(afr[rt][ks], bl8, acc[rt], 0, 0, 0);
            }
        }
        #pragma unroll
        for (int rt = 0; rt < 3; ++rt) {
            float4 o;
            o.x = acc[rt][0]; o.y = acc[rt][1]; o.z = acc[rt][2]; o.w = acc[rt][3];
            *reinterpret_cast<float4*>(&gate[gcol + grow0 + rt*16]) = o;
        }

        asm volatile("s_waitcnt lgkmcnt(0)" ::: "memory");
        __builtin_amdgcn_s_barrier();

        // ---- phase 2: activation, one (j,b) per thread, exact fp32 ----
        const float hr = gate[ab*388 + aj]       + bh_r;
        const float hz = gate[ab*388 + 128 + aj] + bh_z;
        const float hn = gate[ab*388 + 256 + aj] + bh_n;
        const float r = 1.f / (1.f + __expf(-(xr + hr)));
        const float z = 1.f / (1.f + __expf(-(xz + hz)));
        const float x2 = xn + r * hn;
        const float ax = fabsf(x2);
        const float e  = __expf(-2.f * ax);
        const float nn = copysignf((1.f - e) / (1.f + e), x2);  // tanh
        const float hnew = nn + z * (hj - nn);
        hj = hnew;

        const int s = dir ? (S_LEN - 1 - t) : t;
        outs[((size_t)s * 64 + b0 + ab) * 256 + dir * 128 + aj] = hnew;

        const uint32_t hb = bfh(hnew);
        hhi[ab * 136 + aj] = (short)hb;
        hlo[ab * 136 + aj] = (short)f2bf(hnew - __uint_as_float(hb << 16));
        xr = pxr; xz = pxz; xn = pxn;

        asm volatile("s_waitcnt lgkmcnt(0)" ::: "memory");
        __builtin_amdgcn_s_barrier();
    }

    hid_out[dir * (64*128) + (b0 + ab) * 128 + aj] = hj;
}

// ---------------------------------------------------------------------------
// Batch-axis softmax + weighted partial reduction (unchanged)
// ---------------------------------------------------------------------------
__global__ __launch_bounds__(256)
void attn_reduce(const float* __restrict__ lt,    // (S,256,64)
                 const float* __restrict__ outs,  // (S,64,256)
                 float* __restrict__ part)        // (64 chunks,64 b,256 c)
{
    __shared__ float ltile[64 * 64];
    __shared__ float otile[64 * 65];

    const int tid  = threadIdx.x;
    const int lane = tid & 63;
    const int wv   = tid >> 6;
    const int c0   = blockIdx.x * 64;
    const int sc   = blockIdx.y;

    float acc[16];
    #pragma unroll
    for (int i = 0; i < 16; ++i) acc[i] = 0.f;

    for (int si = 0; si < 32; ++si) {
        const int s = sc * 32 + si;

        const float4* src = reinterpret_cast<const float4*>(
            lt + (size_t)s * 16384 + (size_t)c0 * 64);
        #pragma unroll
        for (int i = 0; i < 4; ++i)
            reinterpret_cast<float4*>(ltile)[tid + i * 256] = src[tid + i * 256];

        #pragma unroll
        for (int i = 0; i < 4; ++i) {
            int idx = tid + i * 256;
            int bb = idx >> 4, c4 = (idx & 15) * 4;
            float4 v = *reinterpret_cast<const float4*>(
                &outs[((size_t)s * 64 + bb) * 256 + c0 + c4]);
            otile[bb*65 + c4+0] = v.x; otile[bb*65 + c4+1] = v.y;
            otile[bb*65 + c4+2] = v.z; otile[bb*65 + c4+3] = v.w;
        }
        __syncthreads();

        #pragma unroll
        for (int ci = 0; ci < 16; ++ci) {
            int c = wv * 16 + ci;
            float x = ltile[c * 64 + lane];
            float m = x;
            #pragma unroll
            for (int off = 32; off; off >>= 1)
                m = fmaxf(m, __shfl_xor(m, off));
            float e = __expf(x - m);
            float ssum = e;
            #pragma unroll
            for (int off = 32; off; off >>= 1)
                ssum += __shfl_xor(ssum, off);
            float attn = e / ssum;
            acc[ci] += attn * otile[lane * 65 + c];
        }
        __syncthreads();
    }

    #pragma unroll
    for (int ci = 0; ci < 16; ++ci) {
        int c = wv * 16 + ci;
        part[(size_t)sc * 16384 + (size_t)lane * 256 + c0 + c] = acc[ci];
    }
}

__global__ __launch_bounds__(256)
void reduce_part(const float* __restrict__ part, float* __restrict__ sent)
{
    int idx = blockIdx.x * 256 + threadIdx.x;
    float s = 0.f;
    for (int sc = 0; sc < 64; ++sc)
        s += part[(size_t)sc * 16384 + idx];
    sent[idx] = s;
}

// ---------------------------------------------------------------------------
extern "C" void kernel_launch(void* const* d_in, const int* in_sizes, int n_in,
                              void* d_out, int out_size, void* d_ws, size_t ws_size,
                              hipStream_t stream)
{
    const float* inp    = (const float*)d_in[0];
    const float* hid0   = (const float*)d_in[1];
    const float* w_ih_f = (const float*)d_in[2];
    const float* w_hh_f = (const float*)d_in[3];
    const float* b_ih_f = (const float*)d_in[4];
    const float* b_hh_f = (const float*)d_in[5];
    const float* w_ih_b = (const float*)d_in[6];
    const float* w_hh_b = (const float*)d_in[7];
    const float* b_ih_b = (const float*)d_in[8];
    const float* b_hh_b = (const float*)d_in[9];
    const float* attn_w = (const float*)d_in[10];
    const float* attn_b = (const float*)d_in[11];
    const float* comb_w = (const float*)d_in[12];

    float* out = (float*)d_out;   // [0,16384): sent, [16384,32768): hid_out

    char* ws = (char*)d_ws;
    const size_t XG_BYTES = (size_t)S_LEN * BATCH * 384 * 4;  // 201,326,592
    const size_t OS_BYTES = (size_t)S_LEN * BATCH * 256 * 4;  // 134,217,728
    if (ws_size < 2 * XG_BYTES + OS_BYTES) return;

    float* xg_f   = (float*)(ws);
    float* xg_b   = (float*)(ws + XG_BYTES);
    float* outs   = (float*)(ws + 2 * XG_BYTES);
    float* sa     = (float*)(ws);               // reuse xg_f
    float* logits = (float*)(ws + XG_BYTES);    // reuse xg_b
    float* part   = (float*)(ws);               // reuse sa

    const int M = S_LEN * BATCH;                // 131072
    dim3 blk(256);

    // K1: input-side gates, both directions (MFMA split-bf16)
    gemm_mfma<0><<<dim3(3, 1024), blk, 0, stream>>>(inp, w_ih_f, b_ih_f, xg_f, M, 384, 256);
    gemm_mfma<0><<<dim3(3, 1024), blk, 0, stream>>>(inp, w_ih_b, b_ih_b, xg_b, M, 384, 256);

    // K2: MFMA-batched bidirectional GRU (32 WGs x 512 threads)
    gru_mfma<<<dim3(32), dim3(512), 0, stream>>>(
        xg_f, xg_b, w_hh_f, w_hh_b, b_hh_f, b_hh_b, hid0, outs, out + 16384);

    // K3: sent_annotation = out_state @ attn_w^T + attn_b (MFMA)
    gemm_mfma<0><<<dim3(2, 1024), blk, 0, stream>>>(outs, attn_w, attn_b, sa, M, 256, 256);

    // K4: logits = sa @ comb_w^T, transposed (S,C,B) store (MFMA)
    gemm_mfma<1><<<dim3(2, 1024), blk, 0, stream>>>(sa, comb_w, nullptr, logits, M, 256, 256);

    // K5: softmax over batch + weighted partial sum over s-chunks
    attn_reduce<<<dim3(4, 64), blk, 0, stream>>>(logits, outs, part);

    // K6: final reduction over s-chunks -> sent
    reduce_part<<<dim3(64), blk, 0, stream>>>(part, out);
}